// Round 2
// baseline (155.630 us; speedup 1.0000x reference)
//
#include <hip/hip_runtime.h>
#include <hip/hip_bf16.h>
#include <stdint.h>

typedef __bf16 bf16x8 __attribute__((ext_vector_type(8)));
typedef float floatx4 __attribute__((ext_vector_type(4)));
typedef unsigned short u16;
typedef unsigned int u32;

#define B_    64
#define CIN   64
#define COUT  128
#define H_    1855
#define KNB   6
#define KTOT  448      // (1+KNB)*CIN
#define NSTEPS 14      // KTOT / 32
#define TILE_H 64
#define RS    456      // LDS row stride in elems (448 + 8 pad) -> 912 B, 16B aligned
#define NTILES 29      // ceil(1855/64)

// ws layout (bytes)
#define XT_OFF   0
#define XT_BYTES ((size_t)H_ * 4096 * 2)            // bf16 [1855][4096]
#define WP_OFF   XT_BYTES
#define WP_BYTES ((size_t)COUT * KTOT * 2)          // bf16 [128][448]
#define FLAG_OFF (WP_OFF + WP_BYTES)

static __device__ inline u16 f32_to_bf16(float f) {
    u32 u = __float_as_uint(f);
    u32 r = (u + 0x7FFFu + ((u >> 16) & 1u)) >> 16;
    return (u16)r;
}
static __device__ inline float bf16_to_f32(u16 b) {
    return __uint_as_float(((u32)b) << 16);
}

// ---------------- K0: detect input dtype (1 = bf16-packed, 0 = float32) ----
__global__ __launch_bounds__(256) void k_detect(const u32* __restrict__ x,
                                                int* __restrict__ flag) {
    __shared__ int votes;
    if (threadIdx.x == 0) votes = 0;
    __syncthreads();
    int cnt = 0;
#pragma unroll
    for (int i = 0; i < 4; ++i) {
        u32 w = x[threadIdx.x * 4 + i];
        u32 e = (w >> 7) & 0xFFu;   // low-u16's bf16 exponent field
        cnt += (e >= 115u && e <= 131u) ? 1 : 0;
    }
    atomicAdd(&votes, cnt);
    __syncthreads();
    if (threadIdx.x == 0) *flag = (votes >= 512) ? 1 : 0;
}

// ---------------- K1: transpose x [B*C, H] -> xt [H, B*C] (bf16) ----------
__global__ __launch_bounds__(256) void k_transpose(const void* __restrict__ x,
                                                   u16* __restrict__ xt,
                                                   const int* __restrict__ flag) {
    int isBf = *flag;
    __shared__ u16 tile[64][65];
    int h0  = blockIdx.x * 64;
    int bc0 = blockIdx.y * 64;
    int lane = threadIdx.x & 63;
    int rowq = threadIdx.x >> 6;  // 0..3
#pragma unroll
    for (int i = 0; i < 16; ++i) {
        int row = i * 4 + rowq;          // bc within tile
        int h = h0 + lane;
        u16 v = 0;
        if (h < H_) {
            size_t idx = (size_t)(bc0 + row) * H_ + h;
            v = isBf ? ((const u16*)x)[idx] : f32_to_bf16(((const float*)x)[idx]);
        }
        tile[row][lane] = v;
    }
    __syncthreads();
#pragma unroll
    for (int i = 0; i < 16; ++i) {
        int hr = i * 4 + rowq;           // h within tile
        int h = h0 + hr;
        if (h < H_) xt[(size_t)h * 4096 + bc0 + lane] = tile[lane][hr];
    }
}

// ---------------- K2: pack weights into w_pack[o][s*64 + c] (bf16) --------
__global__ __launch_bounds__(256) void k_pack(const void* __restrict__ wc,
                                              const void* __restrict__ wn,
                                              u16* __restrict__ wp,
                                              const int* __restrict__ flag) {
    int isBf = *flag;
    int tg = blockIdx.x * 256 + threadIdx.x;
    if (tg >= COUT * KTOT) return;
    int o = tg / KTOT;
    int rem = tg - o * KTOT;
    int s = rem >> 6, c = rem & 63;
    int srcIdx = (s == 0) ? (o * CIN + c) : ((o * CIN + c) * KNB + (s - 1));
    u16 v;
    if (s == 0) v = isBf ? ((const u16*)wc)[srcIdx] : f32_to_bf16(((const float*)wc)[srcIdx]);
    else        v = isBf ? ((const u16*)wn)[srcIdx] : f32_to_bf16(((const float*)wn)[srcIdx]);
    wp[tg] = v;
}

// ---------------- K3: main gather-GEMM ----------------
// grid = 64 b * 8 slots = 512 blocks of 256 threads.
// Per h-tile: M=128 (o) over 4 waves (A=W in regs), N=64 (h, coalesced out),
// K=448 = 14 x mfma_f32_16x16x32_bf16.
__global__ __launch_bounds__(256, 2) void k_main(const u16* __restrict__ xt,
                                                 const u16* __restrict__ wp,
                                                 const int* __restrict__ nbr,
                                                 const void* __restrict__ bias,
                                                 const int* __restrict__ flag,
                                                 void* __restrict__ out) {
    __shared__ __align__(16) u16 X[TILE_H * RS];
    __shared__ float cInv[TILE_H];

    int isBf = *flag;
    int tid  = threadIdx.x;
    int b    = blockIdx.x >> 3;
    int slot = blockIdx.x & 7;
    int lane = tid & 63;
    int wave = tid >> 6;
    int col  = lane & 15;
    int quad = lane >> 4;
    int m0w  = wave * 32;

    // Preload A fragments (weights) once per block: A[m=lane&15][k=quad*8+j]
    bf16x8 afrag[2][NSTEPS];
#pragma unroll
    for (int mt = 0; mt < 2; ++mt) {
        int o = m0w + mt * 16 + col;
#pragma unroll
        for (int kk = 0; kk < NSTEPS; ++kk) {
            afrag[mt][kk] = *(const bf16x8*)(wp + o * KTOT + kk * 32 + quad * 8);
        }
    }
    // Bias for this lane's C/D rows (row = quad*4 + r)
    float biasv[2][4];
#pragma unroll
    for (int mt = 0; mt < 2; ++mt)
#pragma unroll
        for (int r = 0; r < 4; ++r) {
            int o = m0w + mt * 16 + quad * 4 + r;
            biasv[mt][r] = isBf ? bf16_to_f32(((const u16*)bias)[o])
                                : ((const float*)bias)[o];
        }

    for (int t = slot; t < NTILES; t += 8) {
        int h0 = t * TILE_H;
        __syncthreads();  // protect LDS from previous iteration's readers

        // per-h 1/count
        if (tid < TILE_H) {
            int h = h0 + tid;
            int cnt = 1;
            if (h < H_) {
#pragma unroll
                for (int j = 0; j < KNB; ++j) cnt += (nbr[h * KNB + j] >= 0) ? 1 : 0;
            }
            cInv[tid] = 1.0f / (float)cnt;
        }

        // stage gathered x tile: X[h_local][s*64 + c], 16B chunks
#pragma unroll
        for (int s = 0; s < 7; ++s) {
#pragma unroll
            for (int r = 0; r < 2; ++r) {
                int idx = r * 256 + tid;   // 0..511
                int hl = idx >> 3;
                int chunk = idx & 7;
                int h = h0 + hl;
                int src = -1;
                if (h < H_) src = (s == 0) ? h : nbr[h * KNB + (s - 1)];
                uint4 v = make_uint4(0u, 0u, 0u, 0u);
                if (src >= 0 && src < H_)
                    v = *(const uint4*)(xt + (size_t)src * 4096 + b * 64 + chunk * 8);
                *(uint4*)(X + hl * RS + s * 64 + chunk * 8) = v;
            }
        }
        __syncthreads();

        // MFMA accumulate
        floatx4 acc[2][4];
#pragma unroll
        for (int mt = 0; mt < 2; ++mt)
#pragma unroll
            for (int nt = 0; nt < 4; ++nt)
                acc[mt][nt] = (floatx4){0.0f, 0.0f, 0.0f, 0.0f};

#pragma unroll
        for (int kk = 0; kk < NSTEPS; ++kk) {
            bf16x8 bfr[4];
#pragma unroll
            for (int nt = 0; nt < 4; ++nt)
                bfr[nt] = *(const bf16x8*)(X + (nt * 16 + col) * RS + kk * 32 + quad * 8);
#pragma unroll
            for (int mt = 0; mt < 2; ++mt)
#pragma unroll
                for (int nt = 0; nt < 4; ++nt)
                    acc[mt][nt] = __builtin_amdgcn_mfma_f32_16x16x32_bf16(
                        afrag[mt][kk], bfr[nt], acc[mt][nt], 0, 0, 0);
        }

        // epilogue: out[b][o][h] = acc/count + bias  (C/D: col=lane&15, row=quad*4+r)
#pragma unroll
        for (int nt = 0; nt < 4; ++nt) {
            int h = h0 + nt * 16 + col;
            if (h < H_) {
                float ic = cInv[nt * 16 + col];
#pragma unroll
                for (int mt = 0; mt < 2; ++mt)
#pragma unroll
                    for (int r = 0; r < 4; ++r) {
                        int o = m0w + mt * 16 + quad * 4 + r;
                        float v = acc[mt][nt][r] * ic + biasv[mt][r];
                        size_t oi = ((size_t)b * COUT + o) * H_ + h;
                        if (isBf) ((u16*)out)[oi] = f32_to_bf16(v);
                        else      ((float*)out)[oi] = v;
                    }
            }
        }
    }
}

extern "C" void kernel_launch(void* const* d_in, const int* in_sizes, int n_in,
                              void* d_out, int out_size, void* d_ws, size_t ws_size,
                              hipStream_t stream) {
    const void* x    = d_in[0];            // [64,64,1855]  f32 or bf16
    const int*  nbr  = (const int*)d_in[1];// int32 [1855,6]
    const void* wc   = d_in[2];            // [128,64]
    const void* wn   = d_in[3];            // [128,64,6]
    const void* bias = d_in[4];            // [128]

    u16* xt  = (u16*)((char*)d_ws + XT_OFF);
    u16* wp  = (u16*)((char*)d_ws + WP_OFF);
    int* flg = (int*)((char*)d_ws + FLAG_OFF);

    k_detect<<<dim3(1), dim3(256), 0, stream>>>((const u32*)x, flg);
    k_pack<<<dim3((COUT * KTOT) / 256), dim3(256), 0, stream>>>(wc, wn, wp, flg);
    k_transpose<<<dim3(NTILES, 64), dim3(256), 0, stream>>>(x, xt, flg);
    k_main<<<dim3(512), dim3(256), 0, stream>>>(xt, wp, nbr, bias, flg, (u16*)d_out);
}

// Round 3
// 146.836 us; speedup vs baseline: 1.0599x; 1.0599x over previous
//
#include <hip/hip_runtime.h>
#include <hip/hip_bf16.h>
#include <stdint.h>

typedef __bf16 bf16x8 __attribute__((ext_vector_type(8)));
typedef float floatx4 __attribute__((ext_vector_type(4)));
typedef unsigned short u16;
typedef unsigned int u32;

#define B_    64
#define CIN   64
#define COUT  128
#define H_    1855
#define KNB   6
#define KTOT  448      // (1+KNB)*CIN
#define NSTEPS 14      // KTOT / 32
#define TILE_H 64
#define RS    456      // LDS row stride elems (448+8 pad) = 912 B
#define NTILES 29      // ceil(1855/64)

static __device__ inline u16 f32_to_bf16(float f) {
    u32 u = __float_as_uint(f);
    u32 r = (u + 0x7FFFu + ((u >> 16) & 1u)) >> 16;
    return (u16)r;
}
static __device__ inline float bf16_to_f32(u16 b) {
    return __uint_as_float(((u32)b) << 16);
}
// dtype self-detect: all threads read the same 16 words -> uniform result.
// bf16-packed: low-u16 exponent of N(0,1) in [115,131] ~always; f32: ~6.6%.
static __device__ inline int detect16(const u32* __restrict__ x) {
    int cnt = 0;
#pragma unroll
    for (int i = 0; i < 16; ++i) {
        u32 e = (x[i] >> 7) & 0xFFu;
        cnt += (e >= 115u && e <= 131u) ? 1 : 0;
    }
    return cnt >= 12;
}

// ---------------- K1: transpose x [b][c][h] -> xt2 [b][h][c] (bf16) -------
__global__ __launch_bounds__(256) void k_transpose(const void* __restrict__ x,
                                                   u16* __restrict__ xt2) {
    int isBf = detect16((const u32*)x);
    __shared__ u16 tile[64][65];
    int h0 = blockIdx.x * 64;
    int b  = blockIdx.y;
    int lane = threadIdx.x & 63;
    int rowq = threadIdx.x >> 6;
    const u16*   xb16 = (const u16*)x + (size_t)b * CIN * H_;
    const float* xb32 = (const float*)x + (size_t)b * CIN * H_;
    int h = h0 + lane;
    bool hv = h < H_;
#pragma unroll
    for (int i = 0; i < 16; ++i) {
        int c = i * 4 + rowq;
        u16 v = 0;
        if (hv) v = isBf ? xb16[c * H_ + h] : f32_to_bf16(xb32[c * H_ + h]);
        tile[c][lane] = v;
    }
    __syncthreads();
#pragma unroll
    for (int i = 0; i < 16; ++i) {
        int hr = i * 4 + rowq;
        int hh = h0 + hr;
        if (hh < H_)
            xt2[((size_t)b * H_ + hh) * 64 + lane] = tile[lane][hr];
    }
}

// ---------------- K2: pack weights into w_pack[o][s*64 + c] (bf16) --------
__global__ __launch_bounds__(256) void k_pack(const void* __restrict__ wc,
                                              const void* __restrict__ wn,
                                              u16* __restrict__ wp,
                                              const u32* __restrict__ xraw) {
    int isBf = detect16(xraw);
    int tg = blockIdx.x * 256 + threadIdx.x;
    if (tg >= COUT * KTOT) return;
    int o = tg / KTOT;
    int rem = tg - o * KTOT;
    int s = rem >> 6, c = rem & 63;
    u16 v;
    if (s == 0) {
        int si = o * CIN + c;
        v = isBf ? ((const u16*)wc)[si] : f32_to_bf16(((const float*)wc)[si]);
    } else {
        int si = (o * CIN + c) * KNB + (s - 1);
        v = isBf ? ((const u16*)wn)[si] : f32_to_bf16(((const float*)wn)[si]);
    }
    wp[tg] = v;
}

// ---------------- K3: main gather-GEMM ----------------
// grid = 960: xcd = blk&7 pins 8 b-slices (1.9 MB of xt2) per XCD -> L2-hot
// gathers. Each block: fixed b, 2 h-tiles. Per tile: M=128 (o, A=W in regs,
// 4 waves x 32 rows), N=64 (h), K=448 = 14 x mfma_f32_16x16x32_bf16.
__global__ __launch_bounds__(256, 2) void k_main(const u16* __restrict__ xt2,
                                                 const u16* __restrict__ wp,
                                                 const int* __restrict__ nbr,
                                                 const void* __restrict__ bias,
                                                 void* __restrict__ out,
                                                 const u32* __restrict__ xraw) {
    __shared__ __align__(16) u16 X[TILE_H * RS];   // staging; reused as out-stage
    __shared__ float cInv[TILE_H];

    int isBf = detect16(xraw);
    int tid  = threadIdx.x;
    int g    = blockIdx.x;
    int xcd  = g & 7;
    int j    = g >> 3;            // 0..119
    int b    = xcd * 8 + (j & 7); // 8 b's per XCD
    int T    = j >> 3;            // 0..14 -> tiles {2T, 2T+1}

    int lane = tid & 63;
    int wave = tid >> 6;
    int col  = lane & 15;
    int quad = lane >> 4;
    int m0w  = wave * 32;

    const u16* xb = xt2 + (size_t)b * (H_ * 64);

    // A fragments (weights) in registers: A[m=lane&15][k=quad*8+j]
    bf16x8 afrag[2][NSTEPS];
#pragma unroll
    for (int mt = 0; mt < 2; ++mt) {
        int o = m0w + mt * 16 + col;
#pragma unroll
        for (int kk = 0; kk < NSTEPS; ++kk)
            afrag[mt][kk] = *(const bf16x8*)(wp + o * KTOT + kk * 32 + quad * 8);
    }
    float biasv[2][4];
#pragma unroll
    for (int mt = 0; mt < 2; ++mt)
#pragma unroll
        for (int r = 0; r < 4; ++r) {
            int o = m0w + mt * 16 + quad * 4 + r;
            biasv[mt][r] = isBf ? bf16_to_f32(((const u16*)bias)[o])
                                : ((const float*)bias)[o];
        }

#pragma unroll
    for (int tt = 0; tt < 2; ++tt) {
        int t = T * 2 + tt;
        if (t >= NTILES) break;
        int h0 = t * TILE_H;
        __syncthreads();   // protect X/cInv from previous iteration's readers

        if (tid < TILE_H) {
            int h = h0 + tid;
            int cnt = 1;
            if (h < H_) {
#pragma unroll
                for (int jj = 0; jj < KNB; ++jj) cnt += (nbr[h * KNB + jj] >= 0) ? 1 : 0;
            }
            cInv[tid] = 1.0f / (float)cnt;
        }

        // stage gathered tile: X[hl][s*64+c] from L2-resident b-slice
#pragma unroll
        for (int r = 0; r < 2; ++r) {
            int idx = r * 256 + tid;       // 0..511
            int hl = idx >> 3, chunk = idx & 7;
            int h = h0 + hl;
            bool hv = h < H_;
            int srcs[7];
            srcs[0] = hv ? h : -1;
#pragma unroll
            for (int s = 1; s < 7; ++s)
                srcs[s] = hv ? nbr[h * KNB + s - 1] : -1;
#pragma unroll
            for (int s = 0; s < 7; ++s) {
                uint4 v = make_uint4(0u, 0u, 0u, 0u);
                if (srcs[s] >= 0)
                    v = *(const uint4*)(xb + (size_t)srcs[s] * 64 + chunk * 8);
                *(uint4*)(X + hl * RS + s * 64 + chunk * 8) = v;
            }
        }
        __syncthreads();

        floatx4 acc[2][4];
#pragma unroll
        for (int mt = 0; mt < 2; ++mt)
#pragma unroll
            for (int nt = 0; nt < 4; ++nt)
                acc[mt][nt] = (floatx4){0.0f, 0.0f, 0.0f, 0.0f};

#pragma unroll
        for (int kk = 0; kk < NSTEPS; ++kk) {
            bf16x8 bfr[4];
#pragma unroll
            for (int nt = 0; nt < 4; ++nt)
                bfr[nt] = *(const bf16x8*)(X + (nt * 16 + col) * RS + kk * 32 + quad * 8);
#pragma unroll
            for (int mt = 0; mt < 2; ++mt)
#pragma unroll
                for (int nt = 0; nt < 4; ++nt)
                    acc[mt][nt] = __builtin_amdgcn_mfma_f32_16x16x32_bf16(
                        afrag[mt][kk], bfr[nt], acc[mt][nt], 0, 0, 0);
        }

        // epilogue: stage C-tile in LDS, then fully-coalesced row stores
        __syncthreads();   // B-frag reads done; X reusable
        int hmax = (H_ - h0 < TILE_H) ? (H_ - h0) : TILE_H;
        if (isBf) {
            u16* stage = X;  // [o][72] u16 (pad for bank spread)
#pragma unroll
            for (int nt = 0; nt < 4; ++nt) {
                float ic = cInv[nt * 16 + col];
#pragma unroll
                for (int mt = 0; mt < 2; ++mt)
#pragma unroll
                    for (int r = 0; r < 4; ++r) {
                        int o = m0w + mt * 16 + quad * 4 + r;
                        stage[o * 72 + nt * 16 + col] =
                            f32_to_bf16(acc[mt][nt][r] * ic + biasv[mt][r]);
                    }
            }
            __syncthreads();
            u16* ob = (u16*)out + (size_t)b * COUT * H_ + h0;
#pragma unroll
            for (int rr = 0; rr < 32; ++rr) {       // one full 128-B row per instr
                int o = m0w + rr;
                if (lane < hmax) ob[(size_t)o * H_ + lane] = stage[o * 72 + lane];
            }
        } else {
            float* stage = (float*)X;  // [o][68] f32
#pragma unroll
            for (int nt = 0; nt < 4; ++nt) {
                float ic = cInv[nt * 16 + col];
#pragma unroll
                for (int mt = 0; mt < 2; ++mt)
#pragma unroll
                    for (int r = 0; r < 4; ++r) {
                        int o = m0w + mt * 16 + quad * 4 + r;
                        stage[o * 68 + nt * 16 + col] = acc[mt][nt][r] * ic + biasv[mt][r];
                    }
            }
            __syncthreads();
            float* ob = (float*)out + (size_t)b * COUT * H_ + h0;
#pragma unroll
            for (int rr = 0; rr < 32; ++rr) {
                int o = m0w + rr;
                if (lane < hmax) ob[(size_t)o * H_ + lane] = stage[o * 68 + lane];
            }
        }
    }
}

extern "C" void kernel_launch(void* const* d_in, const int* in_sizes, int n_in,
                              void* d_out, int out_size, void* d_ws, size_t ws_size,
                              hipStream_t stream) {
    const void* x    = d_in[0];             // [64,64,1855]  f32 or bf16
    const int*  nbr  = (const int*)d_in[1]; // int32 [1855,6]
    const void* wc   = d_in[2];             // [128,64]
    const void* wn   = d_in[3];             // [128,64,6]
    const void* bias = d_in[4];             // [128]

    u16* xt2 = (u16*)d_ws;                                   // [64][1855][64] bf16
    u16* wp  = (u16*)((char*)d_ws + (size_t)B_ * H_ * 64 * 2); // [128][448] bf16

    k_pack<<<dim3((COUT * KTOT) / 256), dim3(256), 0, stream>>>(wc, wn, wp, (const u32*)x);
    k_transpose<<<dim3(NTILES, B_), dim3(256), 0, stream>>>(x, xt2);
    k_main<<<dim3(960), dim3(256), 0, stream>>>(xt2, wp, nbr, bias, d_out, (const u32*)x);
}